// Round 9
// baseline (645.257 us; speedup 1.0000x reference)
//
#include <hip/hip_runtime.h>
#include <hip/hip_bf16.h>

using bf16 = __bf16;
typedef __bf16 bf16x8 __attribute__((ext_vector_type(8)));
typedef __bf16 bf16x4 __attribute__((ext_vector_type(4)));
typedef float  f32x4  __attribute__((ext_vector_type(4)));

#define MFMA16(a, b, c) __builtin_amdgcn_mfma_f32_16x16x32_bf16((a), (b), (c), 0, 0, 0)

// packed weight layout (bf16 element offsets in d_ws); fragment order:
// element j of lane L -> W[kt*32 + (L>>4)*8 + j][nt*16 + (L&15)], zero-padded.
constexpr int P0  = 0;
constexpr int P1  = 16384;
constexpr int P2  = 81920;
constexpr int P3  = 147456;
constexpr int P4  = 212992;
constexpr int P5  = 278528;
constexpr int P6  = 360448;
constexpr int P7  = 425984;
constexpr int PD  = 491520;
constexpr int PC0 = 495616;
constexpr int PC1 = 532480;

constexpr int NPTS = 4096 * 128;
constexpr int SH = 328;   // H stride: 656 B = 41*16 B (odd 16B-stride -> spread banks)

// ------------------------------- pack kernel -------------------------------
struct PackArgs {
    const float* src[11];
    int K[11], N[11], Ntiles[11], tasks[11], dstoff[11];
};

__global__ void nerf_pack(PackArgs pa, bf16* __restrict__ dst) {
    int idx = blockIdx.x * 256 + threadIdx.x;
    for (int l = 0; l < 11; ++l) {
        if (idx < pa.tasks[l]) {
            const int lane = idx & 63;
            const int blk  = idx >> 6;
            const int nt   = blk % pa.Ntiles[l];
            const int kt   = blk / pa.Ntiles[l];
            const int kb   = kt * 32 + (lane >> 4) * 8;
            const int n    = nt * 16 + (lane & 15);
            const float* s = pa.src[l];
            const int K = pa.K[l], N = pa.N[l];
            bf16x8 v;
#pragma unroll
            for (int j = 0; j < 8; ++j) {
                int k = kb + j;
                v[j] = (bf16)((k < K && n < N) ? s[(size_t)k * N + n] : 0.f);
            }
            *(bf16x8*)(dst + pa.dstoff[l] + (size_t)idx * 8) = v;
            return;
        }
        idx -= pa.tasks[l];
    }
}

// ------------------------------- layer -------------------------------------
// Block = 128 threads = 2 waves. In-place C[64,N] = act(H[64,KP] @ Wp + bias).
// Operands swapped: D[m=chan][n=point]; lane holds 4 contiguous chans -> b64 store.
// N=256: waves split chans (NT_W=8 each, weights read once per block).
// N<=128: waves split points (PT_W=2 each).
// MODE 0 -> H (bf16); MODE 1 density -> gout[m0+p]; MODE 2 color -> gout[p*3+c].
template <int KP, int N, bool RELU, int MODE, bool HAZARD>
__device__ __forceinline__ void layer(const bf16* src, bf16* H,
                                      const bf16* __restrict__ wp,
                                      const float* __restrict__ bias,
                                      float* __restrict__ gout, int m0) {
    constexpr int NTILES = N / 16;
    constexpr int NT_W   = (NTILES < 8) ? NTILES : 8;
    constexpr int CG     = NTILES / NT_W;   // chan wave-groups (2 for N=256, else 1)
    constexpr int NPG    = 2 / CG;          // point wave-groups
    constexpr int PT_W   = 4 / NPG;         // point tiles per wave

    const int tid  = threadIdx.x;
    const int lane = tid & 63;
    const int w    = tid >> 6;              // 0..1
    const int l15  = lane & 15;
    const int quad = lane >> 4;
    const int nt0  = (w % CG) * NT_W;
    const int pt0  = (w / CG) * PT_W;

    f32x4 acc[PT_W][NT_W];
    // bias folded into acc init: element r <-> chan (nt0+nt)*16 + quad*4 + r
    if constexpr (MODE == 0) {
#pragma unroll
        for (int nt = 0; nt < NT_W; ++nt) {
            f32x4 b4 = *(const f32x4*)(bias + (nt0 + nt) * 16 + quad * 4);
#pragma unroll
            for (int pt = 0; pt < PT_W; ++pt) acc[pt][nt] = b4;
        }
    } else if constexpr (MODE == 1) {
        const float bv = bias[0];
        f32x4 t = {bv, bv, bv, bv};
#pragma unroll
        for (int pt = 0; pt < PT_W; ++pt) acc[pt][0] = t;
    } else {
        f32x4 t = {bias[0], bias[1], bias[2], 0.f};
#pragma unroll
        for (int pt = 0; pt < PT_W; ++pt) acc[pt][0] = t;
    }

#pragma unroll 2
    for (int kt = 0; kt < KP / 32; ++kt) {
        bf16x8 wf[NT_W];
#pragma unroll
        for (int nt = 0; nt < NT_W; ++nt)
            wf[nt] = *(const bf16x8*)(wp + ((size_t)(kt * NTILES + nt0 + nt) * 64 + lane) * 8);
#pragma unroll
        for (int pt = 0; pt < PT_W; ++pt) {
            const int point = (pt0 + pt) * 16 + l15;
            bf16x8 af = *(const bf16x8*)(src + point * SH + kt * 32 + quad * 8);
#pragma unroll
            for (int nt = 0; nt < NT_W; ++nt)
                acc[pt][nt] = MFMA16(wf[nt], af, acc[pt][nt]);
        }
    }
    if (HAZARD) __syncthreads();   // all in-place reads done before writes

    if constexpr (MODE == 0) {
#pragma unroll
        for (int pt = 0; pt < PT_W; ++pt) {
            const int point = (pt0 + pt) * 16 + l15;
#pragma unroll
            for (int nt = 0; nt < NT_W; ++nt) {
                f32x4 a = acc[pt][nt];
                bf16x4 o;
#pragma unroll
                for (int r = 0; r < 4; ++r) {
                    float v = a[r];
                    if (RELU) v = v > 0.f ? v : 0.f;
                    o[r] = (bf16)v;
                }
                *(bf16x4*)(H + point * SH + (nt0 + nt) * 16 + quad * 4) = o;
            }
        }
        __syncthreads();           // writes visible before next layer reads
    } else if constexpr (MODE == 1) {
        if (quad == 0) {
#pragma unroll
            for (int pt = 0; pt < PT_W; ++pt)
                gout[m0 + (pt0 + pt) * 16 + l15] = acc[pt][0][0];
        }
    } else {
        if (quad == 0) {
#pragma unroll
            for (int pt = 0; pt < PT_W; ++pt) {
                const size_t p3 = (size_t)(m0 + (pt0 + pt) * 16 + l15) * 3;
                gout[p3 + 0] = acc[pt][0][0];
                gout[p3 + 1] = acc[pt][0][1];
                gout[p3 + 2] = acc[pt][0][2];
            }
        }
    }
}

// ------------------------------- main kernel -------------------------------
__global__ __launch_bounds__(128, 2)
void nerf_main(const float* __restrict__ pos, const float* __restrict__ dir,
               const float* __restrict__ b0, const float* __restrict__ b1,
               const float* __restrict__ b2, const float* __restrict__ b3,
               const float* __restrict__ b4, const float* __restrict__ b5,
               const float* __restrict__ b6, const float* __restrict__ b7,
               const float* __restrict__ bd, const float* __restrict__ bc0,
               const float* __restrict__ bc1,
               const bf16* __restrict__ wpk, float* __restrict__ out) {
    __shared__ __align__(16) bf16 H[64 * SH];   // 41984 B -> 3 blocks/CU

    const int m0 = blockIdx.x * 64;
    const int tid = threadIdx.x;

    // zero K-pad cols 316..319 (2 cols per thread as one b32 store)
    *(unsigned int*)(H + (tid & 63) * SH + 316 + 2 * (tid >> 6)) = 0u;

    // positional encoding -> H cols 256..315 (30 cols per thread)
    {
        const int row  = tid >> 1;
        const int half = tid & 1;
        const size_t pb = (size_t)(m0 + row) * 3;
        float xs[3] = { pos[pb], pos[pb + 1], pos[pb + 2] };
#pragma unroll
        for (int j = 0; j < 30; ++j) {
            const int col = half * 30 + j;
            const int c = col / 20, rem = col % 20, s = rem / 10, i = rem % 10;
            const float arg = xs[c] * (float)(1 << i);
            float v = s ? __cosf(arg) : __sinf(arg);
            H[row * SH + 256 + col] = (bf16)v;
        }
    }
    __syncthreads();

    // trunk, in-place; embed_pos lives in cols 256..315 until L5 consumes it
    layer<64,  256, true, 0, false>(H + 256, H, wpk + P0, b0, nullptr, m0);
    layer<256, 256, true, 0, true >(H, H, wpk + P1, b1, nullptr, m0);
    layer<256, 256, true, 0, true >(H, H, wpk + P2, b2, nullptr, m0);
    layer<256, 256, true, 0, true >(H, H, wpk + P3, b3, nullptr, m0);
    layer<256, 256, true, 0, true >(H, H, wpk + P4, b4, nullptr, m0);
    layer<320, 256, true, 0, true >(H, H, wpk + P5, b5, nullptr, m0);  // skip concat
    layer<256, 256, true, 0, true >(H, H, wpk + P6, b6, nullptr, m0);
    layer<256, 256, true, 0, true >(H, H, wpk + P7, b7, nullptr, m0);  // h8 in cols 0..255

    // density head: reads cols 0..255, writes global only (no barrier needed)
    layer<256, 16, false, 1, false>(H, H, wpk + PD, bd, out, m0);

    // dir encoding -> cols 256..279 (12 cols/thread) + zero pads 280..287
    {
        const int row  = tid >> 1;
        const int half = tid & 1;
        const size_t db = (size_t)(m0 + row) * 3;
        float ds[3] = { dir[db], dir[db + 1], dir[db + 2] };
#pragma unroll
        for (int j = 0; j < 12; ++j) {
            const int col = half * 12 + j;
            const int c = col / 8, rem = col % 8, s = rem / 4, i = rem % 4;
            const float arg = ds[c] * (float)(1 << i);
            float v = s ? __cosf(arg) : __sinf(arg);
            H[row * SH + 256 + col] = (bf16)v;
        }
        *(unsigned long long*)(H + row * SH + 280 + half * 4) = 0ull;  // pads
    }
    __syncthreads();

    // color head
    layer<288, 128, true, 0, true >(H, H, wpk + PC0, bc0, nullptr, m0); // c0 -> cols 0..127
    layer<128, 16, false, 2, false>(H, H, wpk + PC1, bc1, out + NPTS, m0);
}

// Loud sentinel if harness I/O layout differs from expectation.
__global__ void nerf_sentinel(float* __restrict__ out, float val) {
    if (threadIdx.x == 0 && blockIdx.x == 0) out[0] = val;
}

// ------------------------------- launcher ----------------------------------
extern "C" void kernel_launch(void* const* d_in, const int* in_sizes, int n_in,
                              void* d_out, int out_size, void* d_ws, size_t ws_size,
                              hipStream_t stream) {
    static const int exp2[24] = {
        1572864, 1572864,
        15360, 256, 65536, 256, 65536, 256, 65536, 256,
        65536, 256, 80896, 256, 65536, 256, 65536, 256,
        256, 1, 35840, 128, 384, 3
    };
    int bad = -1;
    if (n_in != 24) bad = 99;
    else {
        for (int i = 0; i < 24; ++i)
            if (in_sizes[i] != exp2[i]) { bad = i; break; }
    }
    if (bad < 0 && out_size != NPTS * 4) bad = 97;
    if (bad >= 0) {
        nerf_sentinel<<<1, 64, 0, stream>>>((float*)d_out, 20000.f + 100.f * bad);
        return;
    }

    static const int wi[11] = {2, 4, 6, 8, 10, 12, 14, 16, 18, 20, 22};
    static const int Ks[11] = {60, 256, 256, 256, 256, 316, 256, 256, 256, 280, 128};
    static const int Ns[11] = {256, 256, 256, 256, 256, 256, 256, 256, 1, 128, 3};
    static const int Kp[11] = {64, 256, 256, 256, 256, 320, 256, 256, 256, 288, 128};
    static const int Np[11] = {256, 256, 256, 256, 256, 256, 256, 256, 16, 128, 16};

    PackArgs pa;
    int off = 0, total_tasks = 0;
    for (int l = 0; l < 11; ++l) {
        pa.src[l]    = (const float*)d_in[wi[l]];
        pa.K[l]      = Ks[l];
        pa.N[l]      = Ns[l];
        pa.Ntiles[l] = Np[l] / 16;
        pa.tasks[l]  = (Kp[l] / 32) * (Np[l] / 16) * 64;
        pa.dstoff[l] = off;
        off += pa.tasks[l] * 8;
        total_tasks += pa.tasks[l];
    }
    bf16* wpk = (bf16*)d_ws;

    nerf_pack<<<(total_tasks + 255) / 256, 256, 0, stream>>>(pa, wpk);

    nerf_main<<<NPTS / 64, 128, 0, stream>>>(
        (const float*)d_in[0], (const float*)d_in[1],
        (const float*)d_in[3], (const float*)d_in[5], (const float*)d_in[7],
        (const float*)d_in[9], (const float*)d_in[11], (const float*)d_in[13],
        (const float*)d_in[15], (const float*)d_in[17], (const float*)d_in[19],
        (const float*)d_in[21], (const float*)d_in[23],
        wpk, (float*)d_out);
}

// Round 10
// 621.872 us; speedup vs baseline: 1.0376x; 1.0376x over previous
//
#include <hip/hip_runtime.h>
#include <hip/hip_bf16.h>

using bf16 = __bf16;
typedef __bf16 bf16x8 __attribute__((ext_vector_type(8)));
typedef __bf16 bf16x4 __attribute__((ext_vector_type(4)));
typedef float  f32x4  __attribute__((ext_vector_type(4)));

#define MFMA16(a, b, c) __builtin_amdgcn_mfma_f32_16x16x32_bf16((a), (b), (c), 0, 0, 0)

// packed weight layout (bf16 element offsets in d_ws); fragment order:
// element j of lane L -> W[kt*32 + (L>>4)*8 + j][nt*16 + (L&15)], zero-padded.
constexpr int P0  = 0;
constexpr int P1  = 16384;
constexpr int P2  = 81920;
constexpr int P3  = 147456;
constexpr int P4  = 212992;
constexpr int P5  = 278528;
constexpr int P6  = 360448;
constexpr int P7  = 425984;
constexpr int PD  = 491520;
constexpr int PC0 = 495616;
constexpr int PC1 = 532480;

constexpr int NPTS = 4096 * 128;
constexpr int SH = 328;   // H stride: 656 B = 41*16 B; dword-stride 164 ≡ 4 mod 32 banks

// ------------------------------- pack kernel -------------------------------
struct PackArgs {
    const float* src[11];
    int K[11], N[11], Ntiles[11], tasks[11], dstoff[11];
};

__global__ void nerf_pack(PackArgs pa, bf16* __restrict__ dst) {
    int idx = blockIdx.x * 256 + threadIdx.x;
    for (int l = 0; l < 11; ++l) {
        if (idx < pa.tasks[l]) {
            const int lane = idx & 63;
            const int blk  = idx >> 6;
            const int nt   = blk % pa.Ntiles[l];
            const int kt   = blk / pa.Ntiles[l];
            const int kb   = kt * 32 + (lane >> 4) * 8;
            const int n    = nt * 16 + (lane & 15);
            const float* s = pa.src[l];
            const int K = pa.K[l], N = pa.N[l];
            bf16x8 v;
#pragma unroll
            for (int j = 0; j < 8; ++j) {
                int k = kb + j;
                v[j] = (bf16)((k < K && n < N) ? s[(size_t)k * N + n] : 0.f);
            }
            *(bf16x8*)(dst + pa.dstoff[l] + (size_t)idx * 8) = v;
            return;
        }
        idx -= pa.tasks[l];
    }
}

// ------------------------------- layer -------------------------------------
// Block = 512 threads = 8 waves. In-place C[64,N] = act(H[64,KP] @ Wp + bias).
// Operands swapped: D[m=chan][n=point]; lane holds 4 contiguous chans -> b64 store.
// Waves split chans into CG groups (weights read once per block), then points.
// MODE 0 -> H (bf16); MODE 1 density -> gout[m0+p]; MODE 2 color -> gout[p*3+c].
template <int KP, int N, bool RELU, int MODE, bool HAZARD>
__device__ __forceinline__ void layer(const bf16* src, bf16* H,
                                      const bf16* __restrict__ wp,
                                      const float* __restrict__ bias,
                                      float* __restrict__ gout, int m0) {
    constexpr int NW     = 8;                        // waves per block
    constexpr int NTILES = N / 16;
    constexpr int NT_W   = (NTILES >= 16) ? 2 : ((NTILES >= 8) ? 2 : 1);
    constexpr int CG     = NTILES / NT_W;            // chan wave-groups
    static_assert(CG <= NW && NW % CG == 0, "wave split");
    constexpr int NPG    = NW / CG;                  // point wave-groups
    constexpr int PT_W   = (4 + NPG - 1) / NPG;      // point tiles per wave (ceil)

    const int tid  = threadIdx.x;
    const int lane = tid & 63;
    const int w    = tid >> 6;                       // 0..7
    const int l15  = lane & 15;
    const int quad = lane >> 4;
    const int nt0  = (w % CG) * NT_W;
    const int pt0  = (w / CG) * PT_W;
    const bool active = (pt0 < 4);

    f32x4 acc[PT_W][NT_W];
    if (active) {
        // bias folded into acc init: element r <-> chan (nt0+nt)*16 + quad*4 + r
        if constexpr (MODE == 0) {
#pragma unroll
            for (int nt = 0; nt < NT_W; ++nt) {
                f32x4 b4 = *(const f32x4*)(bias + (nt0 + nt) * 16 + quad * 4);
#pragma unroll
                for (int pt = 0; pt < PT_W; ++pt) acc[pt][nt] = b4;
            }
        } else if constexpr (MODE == 1) {
            const float bv = bias[0];
            f32x4 t = {bv, bv, bv, bv};
#pragma unroll
            for (int pt = 0; pt < PT_W; ++pt) acc[pt][0] = t;
        } else {
            f32x4 t = {bias[0], bias[1], bias[2], 0.f};
#pragma unroll
            for (int pt = 0; pt < PT_W; ++pt) acc[pt][0] = t;
        }

#pragma unroll 2
        for (int kt = 0; kt < KP / 32; ++kt) {
            bf16x8 wf[NT_W];
#pragma unroll
            for (int nt = 0; nt < NT_W; ++nt)
                wf[nt] = *(const bf16x8*)(wp + ((size_t)(kt * NTILES + nt0 + nt) * 64 + lane) * 8);
#pragma unroll
            for (int pt = 0; pt < PT_W; ++pt) {
                if (pt0 + pt < 4) {
                    const int point = (pt0 + pt) * 16 + l15;
                    bf16x8 af = *(const bf16x8*)(src + point * SH + kt * 32 + quad * 8);
#pragma unroll
                    for (int nt = 0; nt < NT_W; ++nt)
                        acc[pt][nt] = MFMA16(wf[nt], af, acc[pt][nt]);
                }
            }
        }
    }
    if (HAZARD) __syncthreads();   // all in-place reads done before writes

    if constexpr (MODE == 0) {
        if (active) {
#pragma unroll
            for (int pt = 0; pt < PT_W; ++pt) {
                if (pt0 + pt < 4) {
                    const int point = (pt0 + pt) * 16 + l15;
#pragma unroll
                    for (int nt = 0; nt < NT_W; ++nt) {
                        f32x4 a = acc[pt][nt];
                        bf16x4 o;
#pragma unroll
                        for (int r = 0; r < 4; ++r) {
                            float v = a[r];
                            if (RELU) v = v > 0.f ? v : 0.f;
                            o[r] = (bf16)v;
                        }
                        *(bf16x4*)(H + point * SH + (nt0 + nt) * 16 + quad * 4) = o;
                    }
                }
            }
        }
        __syncthreads();           // writes visible before next layer reads
    } else if constexpr (MODE == 1) {
        if (active && quad == 0) {
#pragma unroll
            for (int pt = 0; pt < PT_W; ++pt)
                if (pt0 + pt < 4)
                    gout[m0 + (pt0 + pt) * 16 + l15] = acc[pt][0][0];
        }
    } else {
        if (active && quad == 0) {
#pragma unroll
            for (int pt = 0; pt < PT_W; ++pt) {
                if (pt0 + pt < 4) {
                    const size_t p3 = (size_t)(m0 + (pt0 + pt) * 16 + l15) * 3;
                    gout[p3 + 0] = acc[pt][0][0];
                    gout[p3 + 1] = acc[pt][0][1];
                    gout[p3 + 2] = acc[pt][0][2];
                }
            }
        }
    }
}

// ------------------------------- main kernel -------------------------------
__global__ __launch_bounds__(512, 6)
void nerf_main(const float* __restrict__ pos, const float* __restrict__ dir,
               const float* __restrict__ b0, const float* __restrict__ b1,
               const float* __restrict__ b2, const float* __restrict__ b3,
               const float* __restrict__ b4, const float* __restrict__ b5,
               const float* __restrict__ b6, const float* __restrict__ b7,
               const float* __restrict__ bd, const float* __restrict__ bc0,
               const float* __restrict__ bc1,
               const bf16* __restrict__ wpk, float* __restrict__ out) {
    __shared__ __align__(16) bf16 H[64 * SH];   // 41984 B -> 3 blocks/CU

    const int m0 = blockIdx.x * 64;
    const int tid = threadIdx.x;

    // positional encoding -> H cols 256..315; cols 316..319 zeroed (K-pad)
    {
        const int row = tid >> 3;          // 0..63
        const int oct = tid & 7;           // 8 cols each
        const size_t pb = (size_t)(m0 + row) * 3;
        float xs[3] = { pos[pb], pos[pb + 1], pos[pb + 2] };
#pragma unroll
        for (int j = 0; j < 8; ++j) {
            const int col = oct * 8 + j;   // 0..63
            float v = 0.f;
            if (col < 60) {
                const int c = col / 20, rem = col % 20, s = rem / 10, i = rem % 10;
                const float arg = xs[c] * (float)(1 << i);
                v = s ? __cosf(arg) : __sinf(arg);
            }
            H[row * SH + 256 + col] = (bf16)v;
        }
    }
    __syncthreads();

    // trunk, in-place; embed_pos lives in cols 256..315 until L5 consumes it
    layer<64,  256, true, 0, false>(H + 256, H, wpk + P0, b0, nullptr, m0);
    layer<256, 256, true, 0, true >(H, H, wpk + P1, b1, nullptr, m0);
    layer<256, 256, true, 0, true >(H, H, wpk + P2, b2, nullptr, m0);
    layer<256, 256, true, 0, true >(H, H, wpk + P3, b3, nullptr, m0);
    layer<256, 256, true, 0, true >(H, H, wpk + P4, b4, nullptr, m0);
    layer<320, 256, true, 0, true >(H, H, wpk + P5, b5, nullptr, m0);  // skip concat
    layer<256, 256, true, 0, true >(H, H, wpk + P6, b6, nullptr, m0);
    layer<256, 256, true, 0, true >(H, H, wpk + P7, b7, nullptr, m0);  // h8 in cols 0..255

    // density head: reads cols 0..255, writes global only (no barrier needed)
    layer<256, 16, false, 1, false>(H, H, wpk + PD, bd, out, m0);

    // dir encoding -> cols 256..279; 280..287 zeroed (c0 K-pad)
    {
        const int row = tid >> 3;
        const int oct = tid & 7;           // 4 cols each
        const size_t db = (size_t)(m0 + row) * 3;
        float ds[3] = { dir[db], dir[db + 1], dir[db + 2] };
#pragma unroll
        for (int j = 0; j < 4; ++j) {
            const int col = oct * 4 + j;   // 0..31
            float v = 0.f;
            if (col < 24) {
                const int c = col / 8, rem = col % 8, s = rem / 4, i = rem % 4;
                const float arg = ds[c] * (float)(1 << i);
                v = s ? __cosf(arg) : __sinf(arg);
            }
            H[row * SH + 256 + col] = (bf16)v;
        }
    }
    __syncthreads();

    // color head
    layer<288, 128, true, 0, true >(H, H, wpk + PC0, bc0, nullptr, m0); // c0 -> cols 0..127
    layer<128, 16, false, 2, false>(H, H, wpk + PC1, bc1, out + NPTS, m0);
}

// Loud sentinel if harness I/O layout differs from expectation.
__global__ void nerf_sentinel(float* __restrict__ out, float val) {
    if (threadIdx.x == 0 && blockIdx.x == 0) out[0] = val;
}

// ------------------------------- launcher ----------------------------------
extern "C" void kernel_launch(void* const* d_in, const int* in_sizes, int n_in,
                              void* d_out, int out_size, void* d_ws, size_t ws_size,
                              hipStream_t stream) {
    static const int exp2[24] = {
        1572864, 1572864,
        15360, 256, 65536, 256, 65536, 256, 65536, 256,
        65536, 256, 80896, 256, 65536, 256, 65536, 256,
        256, 1, 35840, 128, 384, 3
    };
    int bad = -1;
    if (n_in != 24) bad = 99;
    else {
        for (int i = 0; i < 24; ++i)
            if (in_sizes[i] != exp2[i]) { bad = i; break; }
    }
    if (bad < 0 && out_size != NPTS * 4) bad = 97;
    if (bad >= 0) {
        nerf_sentinel<<<1, 64, 0, stream>>>((float*)d_out, 20000.f + 100.f * bad);
        return;
    }

    static const int wi[11] = {2, 4, 6, 8, 10, 12, 14, 16, 18, 20, 22};
    static const int Ks[11] = {60, 256, 256, 256, 256, 316, 256, 256, 256, 280, 128};
    static const int Ns[11] = {256, 256, 256, 256, 256, 256, 256, 256, 1, 128, 3};
    static const int Kp[11] = {64, 256, 256, 256, 256, 320, 256, 256, 256, 288, 128};
    static const int Np[11] = {256, 256, 256, 256, 256, 256, 256, 256, 16, 128, 16};

    PackArgs pa;
    int off = 0, total_tasks = 0;
    for (int l = 0; l < 11; ++l) {
        pa.src[l]    = (const float*)d_in[wi[l]];
        pa.K[l]      = Ks[l];
        pa.N[l]      = Ns[l];
        pa.Ntiles[l] = Np[l] / 16;
        pa.tasks[l]  = (Kp[l] / 32) * (Np[l] / 16) * 64;
        pa.dstoff[l] = off;
        off += pa.tasks[l] * 8;
        total_tasks += pa.tasks[l];
    }
    bf16* wpk = (bf16*)d_ws;

    nerf_pack<<<(total_tasks + 255) / 256, 256, 0, stream>>>(pa, wpk);

    nerf_main<<<NPTS / 64, 512, 0, stream>>>(
        (const float*)d_in[0], (const float*)d_in[1],
        (const float*)d_in[3], (const float*)d_in[5], (const float*)d_in[7],
        (const float*)d_in[9], (const float*)d_in[11], (const float*)d_in[13],
        (const float*)d_in[15], (const float*)d_in[17], (const float*)d_in[19],
        (const float*)d_in[21], (const float*)d_in[23],
        wpk, (float*)d_out);
}

// Round 11
// 617.686 us; speedup vs baseline: 1.0446x; 1.0068x over previous
//
#include <hip/hip_runtime.h>
#include <hip/hip_bf16.h>

using bf16 = __bf16;
typedef __bf16 bf16x8 __attribute__((ext_vector_type(8)));
typedef __bf16 bf16x4 __attribute__((ext_vector_type(4)));
typedef float  f32x4  __attribute__((ext_vector_type(4)));

#define MFMA16(a, b, c) __builtin_amdgcn_mfma_f32_16x16x32_bf16((a), (b), (c), 0, 0, 0)

// packed weight layout (bf16 element offsets in d_ws); fragment order:
// element j of lane L -> W[kt*32 + (L>>4)*8 + j][nt*16 + (L&15)], zero-padded.
constexpr int P0  = 0;
constexpr int P1  = 16384;
constexpr int P2  = 81920;
constexpr int P3  = 147456;
constexpr int P4  = 212992;
constexpr int P5  = 278528;
constexpr int P6  = 360448;
constexpr int P7  = 425984;
constexpr int PD  = 491520;
constexpr int PC0 = 495616;
constexpr int PC1 = 532480;

constexpr int NPTS = 4096 * 128;
constexpr int SH = 320;   // 40 chunks of 8 bf16 (16B) per row; XOR-swizzled banks

// H layout: element (row p, col c) lives at p*SH + ((c>>3) ^ (p&7))*8 + (c&7).
// Bijective per row -> correctness independent of swizzle; kills the
// 8-lanes-per-bank-group pattern of ds_read_b128 (dword stride 160 ≡ 0 mod 32,
// chunk XOR spreads the 8 chunk-groups across all 32 banks).

// ------------------------------- pack kernel -------------------------------
struct PackArgs {
    const float* src[11];
    int K[11], N[11], Ntiles[11], tasks[11], dstoff[11];
};

__global__ void nerf_pack(PackArgs pa, bf16* __restrict__ dst) {
    int idx = blockIdx.x * 256 + threadIdx.x;
    for (int l = 0; l < 11; ++l) {
        if (idx < pa.tasks[l]) {
            const int lane = idx & 63;
            const int blk  = idx >> 6;
            const int nt   = blk % pa.Ntiles[l];
            const int kt   = blk / pa.Ntiles[l];
            const int kb   = kt * 32 + (lane >> 4) * 8;
            const int n    = nt * 16 + (lane & 15);
            const float* s = pa.src[l];
            const int K = pa.K[l], N = pa.N[l];
            bf16x8 v;
#pragma unroll
            for (int j = 0; j < 8; ++j) {
                int k = kb + j;
                v[j] = (bf16)((k < K && n < N) ? s[(size_t)k * N + n] : 0.f);
            }
            *(bf16x8*)(dst + pa.dstoff[l] + (size_t)idx * 8) = v;
            return;
        }
        idx -= pa.tasks[l];
    }
}

// ------------------------------- layer -------------------------------------
// Block = 512 threads = 8 waves. In-place C[64,N] = act(H[64,KP] @ Wp + bias).
// Operands swapped: D[m=chan][n=point]. Waves split chans (CG groups; weights
// read once per block), then points. COFF = source column offset (swizzled).
template <int KP, int N, bool RELU, int MODE, bool HAZARD, int COFF>
__device__ __forceinline__ void layer(bf16* H,
                                      const bf16* __restrict__ wp,
                                      const float* __restrict__ bias,
                                      float* __restrict__ gout, int m0) {
    constexpr int NW     = 8;
    constexpr int NTILES = N / 16;
    constexpr int NT_W   = (NTILES >= 8) ? 2 : 1;
    constexpr int CG     = NTILES / NT_W;            // chan wave-groups
    static_assert(CG <= NW && NW % CG == 0, "wave split");
    constexpr int NPG    = NW / CG;
    constexpr int PT_W   = (4 + NPG - 1) / NPG;      // point tiles per wave

    const int tid  = threadIdx.x;
    const int lane = tid & 63;
    const int w    = tid >> 6;
    const int l15  = lane & 15;
    const int quad = lane >> 4;
    const int swz  = l15 & 7;                        // point%8 per lane
    const int nt0  = (w % CG) * NT_W;
    const int pt0  = (w / CG) * PT_W;
    const bool active = (pt0 < 4);

    f32x4 acc[PT_W][NT_W];
    if (active) {
        if constexpr (MODE == 0) {
#pragma unroll
            for (int nt = 0; nt < NT_W; ++nt) {
                f32x4 b4 = *(const f32x4*)(bias + (nt0 + nt) * 16 + quad * 4);
#pragma unroll
                for (int pt = 0; pt < PT_W; ++pt) acc[pt][nt] = b4;
            }
        } else if constexpr (MODE == 1) {
            const float bv = bias[0];
            f32x4 t = {bv, bv, bv, bv};
#pragma unroll
            for (int pt = 0; pt < PT_W; ++pt) acc[pt][0] = t;
        } else {
            f32x4 t = {bias[0], bias[1], bias[2], 0.f};
#pragma unroll
            for (int pt = 0; pt < PT_W; ++pt) acc[pt][0] = t;
        }

#pragma unroll 2
        for (int kt = 0; kt < KP / 32; ++kt) {
            bf16x8 wf[NT_W];
#pragma unroll
            for (int nt = 0; nt < NT_W; ++nt)
                wf[nt] = *(const bf16x8*)(wp + ((size_t)(kt * NTILES + nt0 + nt) * 64 + lane) * 8);
#pragma unroll
            for (int pt = 0; pt < PT_W; ++pt) {
                if (pt0 + pt < 4) {
                    const int point = (pt0 + pt) * 16 + l15;
                    const int chunk = (COFF >> 3) + kt * 4 + quad;
                    bf16x8 af = *(const bf16x8*)(H + point * SH + ((chunk ^ swz) << 3));
#pragma unroll
                    for (int nt = 0; nt < NT_W; ++nt)
                        acc[pt][nt] = MFMA16(wf[nt], af, acc[pt][nt]);
                }
            }
        }
    }
    if (HAZARD) __syncthreads();   // all in-place reads done before writes

    if constexpr (MODE == 0) {
        if (active) {
#pragma unroll
            for (int pt = 0; pt < PT_W; ++pt) {
                if (pt0 + pt < 4) {
                    const int point = (pt0 + pt) * 16 + l15;
#pragma unroll
                    for (int nt = 0; nt < NT_W; ++nt) {
                        f32x4 a = acc[pt][nt];
                        bf16x4 o;
#pragma unroll
                        for (int r = 0; r < 4; ++r) {
                            float v = a[r];
                            if (RELU) v = v > 0.f ? v : 0.f;
                            o[r] = (bf16)v;
                        }
                        const int chunk = (nt0 + nt) * 2 + (quad >> 1);
                        *(bf16x4*)(H + point * SH + ((chunk ^ swz) << 3) + (quad & 1) * 4) = o;
                    }
                }
            }
        }
        __syncthreads();           // writes visible before next layer reads
    } else if constexpr (MODE == 1) {
        if (active && quad == 0) {
#pragma unroll
            for (int pt = 0; pt < PT_W; ++pt)
                if (pt0 + pt < 4)
                    gout[m0 + (pt0 + pt) * 16 + l15] = acc[pt][0][0];
        }
    } else {
        if (active && quad == 0) {
#pragma unroll
            for (int pt = 0; pt < PT_W; ++pt) {
                if (pt0 + pt < 4) {
                    const size_t p3 = (size_t)(m0 + (pt0 + pt) * 16 + l15) * 3;
                    gout[p3 + 0] = acc[pt][0][0];
                    gout[p3 + 1] = acc[pt][0][1];
                    gout[p3 + 2] = acc[pt][0][2];
                }
            }
        }
    }
}

// ------------------------------- main kernel -------------------------------
__global__ __launch_bounds__(512, 6)
void nerf_main(const float* __restrict__ pos, const float* __restrict__ dir,
               const float* __restrict__ b0, const float* __restrict__ b1,
               const float* __restrict__ b2, const float* __restrict__ b3,
               const float* __restrict__ b4, const float* __restrict__ b5,
               const float* __restrict__ b6, const float* __restrict__ b7,
               const float* __restrict__ bd, const float* __restrict__ bc0,
               const float* __restrict__ bc1,
               const bf16* __restrict__ wpk, float* __restrict__ out) {
    __shared__ __align__(16) bf16 H[64 * SH];   // 40960 B -> 3 blocks/CU

    const int m0 = blockIdx.x * 64;
    const int tid = threadIdx.x;

    // positional encoding -> cols 256..315; 316..319 zeroed (K-pad).
    // Each thread writes 8 cols = exactly one 16B chunk (swizzled).
    {
        const int row = tid >> 3;          // 0..63
        const int oct = tid & 7;           // chunk 32+oct
        const int swz = row & 7;
        const size_t pb = (size_t)(m0 + row) * 3;
        float xs[3] = { pos[pb], pos[pb + 1], pos[pb + 2] };
        bf16* dst = H + row * SH + (((32 + oct) ^ swz) << 3);
#pragma unroll
        for (int j = 0; j < 8; ++j) {
            const int col = oct * 8 + j;   // 0..63
            float v = 0.f;
            if (col < 60) {
                const int c = col / 20, rem = col % 20, s = rem / 10, i = rem % 10;
                const float arg = xs[c] * (float)(1 << i);
                v = s ? __cosf(arg) : __sinf(arg);
            }
            dst[j] = (bf16)v;
        }
    }
    __syncthreads();

    // trunk, in-place; embed_pos lives in cols 256..315 until L5 consumes it
    layer<64,  256, true, 0, false, 256>(H, wpk + P0, b0, nullptr, m0);
    layer<256, 256, true, 0, true,  0  >(H, wpk + P1, b1, nullptr, m0);
    layer<256, 256, true, 0, true,  0  >(H, wpk + P2, b2, nullptr, m0);
    layer<256, 256, true, 0, true,  0  >(H, wpk + P3, b3, nullptr, m0);
    layer<256, 256, true, 0, true,  0  >(H, wpk + P4, b4, nullptr, m0);
    layer<320, 256, true, 0, true,  0  >(H, wpk + P5, b5, nullptr, m0);  // skip concat
    layer<256, 256, true, 0, true,  0  >(H, wpk + P6, b6, nullptr, m0);
    layer<256, 256, true, 0, true,  0  >(H, wpk + P7, b7, nullptr, m0);  // h8 -> cols 0..255

    // density head: reads cols 0..255, writes global only (no barrier needed)
    layer<256, 16, false, 1, false, 0>(H, wpk + PD, bd, out, m0);

    // dir encoding -> cols 256..279; 280..287 zeroed (c0 K-pad); chunks 32..35
    // are disjoint from density's reads (chunks 0..31), so no barrier before.
    {
        const int row = tid >> 3;
        const int oct = tid & 7;           // 4 cols each
        const int swz = row & 7;
        const size_t db = (size_t)(m0 + row) * 3;
        float ds[3] = { dir[db], dir[db + 1], dir[db + 2] };
        const int chunk = 32 + (oct >> 1);
        bf16* dst = H + row * SH + ((chunk ^ swz) << 3) + (oct & 1) * 4;
#pragma unroll
        for (int j = 0; j < 4; ++j) {
            const int col = oct * 4 + j;   // 0..31
            float v = 0.f;
            if (col < 24) {
                const int c = col / 8, rem = col % 8, s = rem / 4, i = rem % 4;
                const float arg = ds[c] * (float)(1 << i);
                v = s ? __cosf(arg) : __sinf(arg);
            }
            dst[j] = (bf16)v;
        }
    }
    __syncthreads();

    // color head
    layer<288, 128, true, 0, true,  0>(H, wpk + PC0, bc0, nullptr, m0); // c0 -> cols 0..127
    layer<128, 16, false, 2, false, 0>(H, wpk + PC1, bc1, out + NPTS, m0);
}

// Loud sentinel if harness I/O layout differs from expectation.
__global__ void nerf_sentinel(float* __restrict__ out, float val) {
    if (threadIdx.x == 0 && blockIdx.x == 0) out[0] = val;
}

// ------------------------------- launcher ----------------------------------
extern "C" void kernel_launch(void* const* d_in, const int* in_sizes, int n_in,
                              void* d_out, int out_size, void* d_ws, size_t ws_size,
                              hipStream_t stream) {
    static const int exp2[24] = {
        1572864, 1572864,
        15360, 256, 65536, 256, 65536, 256, 65536, 256,
        65536, 256, 80896, 256, 65536, 256, 65536, 256,
        256, 1, 35840, 128, 384, 3
    };
    int bad = -1;
    if (n_in != 24) bad = 99;
    else {
        for (int i = 0; i < 24; ++i)
            if (in_sizes[i] != exp2[i]) { bad = i; break; }
    }
    if (bad < 0 && out_size != NPTS * 4) bad = 97;
    if (bad >= 0) {
        nerf_sentinel<<<1, 64, 0, stream>>>((float*)d_out, 20000.f + 100.f * bad);
        return;
    }

    static const int wi[11] = {2, 4, 6, 8, 10, 12, 14, 16, 18, 20, 22};
    static const int Ks[11] = {60, 256, 256, 256, 256, 316, 256, 256, 256, 280, 128};
    static const int Ns[11] = {256, 256, 256, 256, 256, 256, 256, 256, 1, 128, 3};
    static const int Kp[11] = {64, 256, 256, 256, 256, 320, 256, 256, 256, 288, 128};
    static const int Np[11] = {256, 256, 256, 256, 256, 256, 256, 256, 16, 128, 16};

    PackArgs pa;
    int off = 0, total_tasks = 0;
    for (int l = 0; l < 11; ++l) {
        pa.src[l]    = (const float*)d_in[wi[l]];
        pa.K[l]      = Ks[l];
        pa.N[l]      = Ns[l];
        pa.Ntiles[l] = Np[l] / 16;
        pa.tasks[l]  = (Kp[l] / 32) * (Np[l] / 16) * 64;
        pa.dstoff[l] = off;
        off += pa.tasks[l] * 8;
        total_tasks += pa.tasks[l];
    }
    bf16* wpk = (bf16*)d_ws;

    nerf_pack<<<(total_tasks + 255) / 256, 256, 0, stream>>>(pa, wpk);

    nerf_main<<<NPTS / 64, 512, 0, stream>>>(
        (const float*)d_in[0], (const float*)d_in[1],
        (const float*)d_in[3], (const float*)d_in[5], (const float*)d_in[7],
        (const float*)d_in[9], (const float*)d_in[11], (const float*)d_in[13],
        (const float*)d_in[15], (const float*)d_in[17], (const float*)d_in[19],
        (const float*)d_in[21], (const float*)d_in[23],
        wpk, (float*)d_out);
}

// Round 12
// 585.968 us; speedup vs baseline: 1.1012x; 1.0541x over previous
//
#include <hip/hip_runtime.h>
#include <hip/hip_bf16.h>

using bf16 = __bf16;
typedef __bf16 bf16x8 __attribute__((ext_vector_type(8)));
typedef __bf16 bf16x4 __attribute__((ext_vector_type(4)));
typedef float  f32x4  __attribute__((ext_vector_type(4)));

#define MFMA16(a, b, c) __builtin_amdgcn_mfma_f32_16x16x32_bf16((a), (b), (c), 0, 0, 0)

// packed weight layout (bf16 element offsets in d_ws); fragment order:
// element j of lane L -> W[kt*32 + (L>>4)*8 + j][nt*16 + (L&15)], zero-padded.
constexpr int P0  = 0;
constexpr int P1  = 16384;
constexpr int P2  = 81920;
constexpr int P3  = 147456;
constexpr int P4  = 212992;
constexpr int P5  = 278528;
constexpr int P6  = 360448;
constexpr int P7  = 425984;
constexpr int PD  = 491520;
constexpr int PC0 = 495616;
constexpr int PC1 = 532480;

constexpr int NPTS = 4096 * 128;
constexpr int MT = 128;        // points per block
constexpr int PTILES = MT / 16;
constexpr int SH = 320;        // 40 chunks of 8 bf16 (16B); XOR-swizzled

// H layout: element (row p, col c) at p*SH + ((c>>3) ^ (p&7))*8 + (c&7).

// ------------------------------- pack kernel -------------------------------
struct PackArgs {
    const float* src[11];
    int K[11], N[11], Ntiles[11], tasks[11], dstoff[11];
};

__global__ void nerf_pack(PackArgs pa, bf16* __restrict__ dst) {
    int idx = blockIdx.x * 256 + threadIdx.x;
    for (int l = 0; l < 11; ++l) {
        if (idx < pa.tasks[l]) {
            const int lane = idx & 63;
            const int blk  = idx >> 6;
            const int nt   = blk % pa.Ntiles[l];
            const int kt   = blk / pa.Ntiles[l];
            const int kb   = kt * 32 + (lane >> 4) * 8;
            const int n    = nt * 16 + (lane & 15);
            const float* s = pa.src[l];
            const int K = pa.K[l], N = pa.N[l];
            bf16x8 v;
#pragma unroll
            for (int j = 0; j < 8; ++j) {
                int k = kb + j;
                v[j] = (bf16)((k < K && n < N) ? s[(size_t)k * N + n] : 0.f);
            }
            *(bf16x8*)(dst + pa.dstoff[l] + (size_t)idx * 8) = v;
            return;
        }
        idx -= pa.tasks[l];
    }
}

// ------------------------------- layer -------------------------------------
// Block = 512 threads = 8 waves, M=128 points. In-place C = act(H @ Wp + b).
// Operands swapped: D[m=chan][n=point]. NT_W=4 for N=256 (CG=4, NPG=2, PT_W=4)
// halves LDS af traffic per point vs CG=8. COFF = source column offset.
template <int KP, int N, bool RELU, int MODE, bool HAZARD, int COFF>
__device__ __forceinline__ void layer(bf16* H,
                                      const bf16* __restrict__ wp,
                                      const float* __restrict__ bias,
                                      float* __restrict__ gout, int m0) {
    constexpr int NW     = 8;
    constexpr int NTILES = N / 16;
    constexpr int NT_W   = (NTILES >= 16) ? 4 : ((NTILES >= 8) ? 2 : 1);
    constexpr int CG     = NTILES / NT_W;            // chan wave-groups
    static_assert(CG <= NW && NW % CG == 0, "wave split");
    constexpr int NPG    = NW / CG;                  // point wave-groups
    constexpr int PT_W   = PTILES / NPG;             // point tiles per wave

    const int tid  = threadIdx.x;
    const int lane = tid & 63;
    const int w    = tid >> 6;
    const int l15  = lane & 15;
    const int quad = lane >> 4;
    const int swz  = l15 & 7;
    const int nt0  = (w % CG) * NT_W;
    const int pt0  = (w / CG) * PT_W;

    f32x4 acc[PT_W][NT_W];
    if constexpr (MODE == 0) {
#pragma unroll
        for (int nt = 0; nt < NT_W; ++nt) {
            f32x4 b4 = *(const f32x4*)(bias + (nt0 + nt) * 16 + quad * 4);
#pragma unroll
            for (int pt = 0; pt < PT_W; ++pt) acc[pt][nt] = b4;
        }
    } else if constexpr (MODE == 1) {
        const float bv = bias[0];
        f32x4 t = {bv, bv, bv, bv};
#pragma unroll
        for (int pt = 0; pt < PT_W; ++pt) acc[pt][0] = t;
    } else {
        f32x4 t = {bias[0], bias[1], bias[2], 0.f};
#pragma unroll
        for (int pt = 0; pt < PT_W; ++pt) acc[pt][0] = t;
    }

#pragma unroll 2
    for (int kt = 0; kt < KP / 32; ++kt) {
        bf16x8 wf[NT_W];
#pragma unroll
        for (int nt = 0; nt < NT_W; ++nt)
            wf[nt] = *(const bf16x8*)(wp + ((size_t)(kt * NTILES + nt0 + nt) * 64 + lane) * 8);
#pragma unroll
        for (int pt = 0; pt < PT_W; ++pt) {
            const int point = (pt0 + pt) * 16 + l15;
            const int chunk = (COFF >> 3) + kt * 4 + quad;
            bf16x8 af = *(const bf16x8*)(H + point * SH + ((chunk ^ swz) << 3));
#pragma unroll
            for (int nt = 0; nt < NT_W; ++nt)
                acc[pt][nt] = MFMA16(wf[nt], af, acc[pt][nt]);
        }
    }
    if (HAZARD) __syncthreads();   // all in-place reads done before writes

    if constexpr (MODE == 0) {
#pragma unroll
        for (int pt = 0; pt < PT_W; ++pt) {
            const int point = (pt0 + pt) * 16 + l15;
#pragma unroll
            for (int nt = 0; nt < NT_W; ++nt) {
                f32x4 a = acc[pt][nt];
                bf16x4 o;
#pragma unroll
                for (int r = 0; r < 4; ++r) {
                    float v = a[r];
                    if (RELU) v = v > 0.f ? v : 0.f;
                    o[r] = (bf16)v;
                }
                const int chunk = (nt0 + nt) * 2 + (quad >> 1);
                *(bf16x4*)(H + point * SH + ((chunk ^ swz) << 3) + (quad & 1) * 4) = o;
            }
        }
        __syncthreads();           // writes visible before next layer reads
    } else if constexpr (MODE == 1) {
        if (quad == 0) {
#pragma unroll
            for (int pt = 0; pt < PT_W; ++pt)
                gout[m0 + (pt0 + pt) * 16 + l15] = acc[pt][0][0];
        }
    } else {
        if (quad == 0) {
#pragma unroll
            for (int pt = 0; pt < PT_W; ++pt) {
                const size_t p3 = (size_t)(m0 + (pt0 + pt) * 16 + l15) * 3;
                gout[p3 + 0] = acc[pt][0][0];
                gout[p3 + 1] = acc[pt][0][1];
                gout[p3 + 2] = acc[pt][0][2];
            }
        }
    }
}

// ------------------------------- main kernel -------------------------------
__global__ __launch_bounds__(512, 4)
void nerf_main(const float* __restrict__ pos, const float* __restrict__ dir,
               const float* __restrict__ b0, const float* __restrict__ b1,
               const float* __restrict__ b2, const float* __restrict__ b3,
               const float* __restrict__ b4, const float* __restrict__ b5,
               const float* __restrict__ b6, const float* __restrict__ b7,
               const float* __restrict__ bd, const float* __restrict__ bc0,
               const float* __restrict__ bc1,
               const bf16* __restrict__ wpk, float* __restrict__ out) {
    __shared__ __align__(16) bf16 H[MT * SH];   // 81920 B -> 2 blocks/CU

    const int m0 = blockIdx.x * MT;
    const int tid = threadIdx.x;

    // positional encoding -> cols 256..315; 316..319 zeroed (K-pad).
    // 4 threads/row; each writes 2 swizzled 16B chunks (16 cols).
    {
        const int row = tid >> 2;          // 0..127
        const int sub = tid & 3;
        const int swz = row & 7;
        const size_t pb = (size_t)(m0 + row) * 3;
        float xs[3] = { pos[pb], pos[pb + 1], pos[pb + 2] };
#pragma unroll
        for (int h = 0; h < 2; ++h) {
            const int chunk = 32 + sub * 2 + h;
            bf16* dst = H + row * SH + ((chunk ^ swz) << 3);
#pragma unroll
            for (int j = 0; j < 8; ++j) {
                const int col = sub * 16 + h * 8 + j;   // 0..63
                float v = 0.f;
                if (col < 60) {
                    const int c = col / 20, rem = col % 20, s = rem / 10, i = rem % 10;
                    const float arg = xs[c] * (float)(1 << i);
                    v = s ? __cosf(arg) : __sinf(arg);
                }
                dst[j] = (bf16)v;
            }
        }
    }
    __syncthreads();

    // trunk, in-place; embed_pos lives in cols 256..315 until L5 consumes it
    layer<64,  256, true, 0, false, 256>(H, wpk + P0, b0, nullptr, m0);
    layer<256, 256, true, 0, true,  0  >(H, wpk + P1, b1, nullptr, m0);
    layer<256, 256, true, 0, true,  0  >(H, wpk + P2, b2, nullptr, m0);
    layer<256, 256, true, 0, true,  0  >(H, wpk + P3, b3, nullptr, m0);
    layer<256, 256, true, 0, true,  0  >(H, wpk + P4, b4, nullptr, m0);
    layer<320, 256, true, 0, true,  0  >(H, wpk + P5, b5, nullptr, m0);  // skip concat
    layer<256, 256, true, 0, true,  0  >(H, wpk + P6, b6, nullptr, m0);
    layer<256, 256, true, 0, true,  0  >(H, wpk + P7, b7, nullptr, m0);  // h8 -> cols 0..255

    // density head: reads chunks 0..31, writes global only
    layer<256, 16, false, 1, false, 0>(H, wpk + PD, bd, out, m0);

    // dir encoding -> cols 256..279; 280..287 zeroed (c0 K-pad); chunks 32..35
    // disjoint from density's reads -> no barrier before.
    {
        const int row = tid >> 2;
        const int sub = tid & 3;
        const int swz = row & 7;
        const size_t db = (size_t)(m0 + row) * 3;
        float ds[3] = { dir[db], dir[db + 1], dir[db + 2] };
        const int chunk = 32 + sub;
        bf16* dst = H + row * SH + ((chunk ^ swz) << 3);
#pragma unroll
        for (int j = 0; j < 8; ++j) {
            const int col = sub * 8 + j;   // 0..31
            float v = 0.f;
            if (col < 24) {
                const int c = col / 8, rem = col % 8, s = rem / 4, i = rem % 4;
                const float arg = ds[c] * (float)(1 << i);
                v = s ? __cosf(arg) : __sinf(arg);
            }
            dst[j] = (bf16)v;
        }
    }
    __syncthreads();

    // color head
    layer<288, 128, true, 0, true,  0>(H, wpk + PC0, bc0, nullptr, m0); // c0 -> cols 0..127
    layer<128, 16, false, 2, false, 0>(H, wpk + PC1, bc1, out + NPTS, m0);
}

// Loud sentinel if harness I/O layout differs from expectation.
__global__ void nerf_sentinel(float* __restrict__ out, float val) {
    if (threadIdx.x == 0 && blockIdx.x == 0) out[0] = val;
}

// ------------------------------- launcher ----------------------------------
extern "C" void kernel_launch(void* const* d_in, const int* in_sizes, int n_in,
                              void* d_out, int out_size, void* d_ws, size_t ws_size,
                              hipStream_t stream) {
    static const int exp2[24] = {
        1572864, 1572864,
        15360, 256, 65536, 256, 65536, 256, 65536, 256,
        65536, 256, 80896, 256, 65536, 256, 65536, 256,
        256, 1, 35840, 128, 384, 3
    };
    int bad = -1;
    if (n_in != 24) bad = 99;
    else {
        for (int i = 0; i < 24; ++i)
            if (in_sizes[i] != exp2[i]) { bad = i; break; }
    }
    if (bad < 0 && out_size != NPTS * 4) bad = 97;
    if (bad >= 0) {
        nerf_sentinel<<<1, 64, 0, stream>>>((float*)d_out, 20000.f + 100.f * bad);
        return;
    }

    static const int wi[11] = {2, 4, 6, 8, 10, 12, 14, 16, 18, 20, 22};
    static const int Ks[11] = {60, 256, 256, 256, 256, 316, 256, 256, 256, 280, 128};
    static const int Ns[11] = {256, 256, 256, 256, 256, 256, 256, 256, 1, 128, 3};
    static const int Kp[11] = {64, 256, 256, 256, 256, 320, 256, 256, 256, 288, 128};
    static const int Np[11] = {256, 256, 256, 256, 256, 256, 256, 256, 16, 128, 16};

    PackArgs pa;
    int off = 0, total_tasks = 0;
    for (int l = 0; l < 11; ++l) {
        pa.src[l]    = (const float*)d_in[wi[l]];
        pa.K[l]      = Ks[l];
        pa.N[l]      = Ns[l];
        pa.Ntiles[l] = Np[l] / 16;
        pa.tasks[l]  = (Kp[l] / 32) * (Np[l] / 16) * 64;
        pa.dstoff[l] = off;
        off += pa.tasks[l] * 8;
        total_tasks += pa.tasks[l];
    }
    bf16* wpk = (bf16*)d_ws;

    nerf_pack<<<(total_tasks + 255) / 256, 256, 0, stream>>>(pa, wpk);

    nerf_main<<<NPTS / MT, 512, 0, stream>>>(
        (const float*)d_in[0], (const float*)d_in[1],
        (const float*)d_in[3], (const float*)d_in[5], (const float*)d_in[7],
        (const float*)d_in[9], (const float*)d_in[11], (const float*)d_in[13],
        (const float*)d_in[15], (const float*)d_in[17], (const float*)d_in[19],
        (const float*)d_in[21], (const float*)d_in[23],
        wpk, (float*)d_out);
}